// Round 1
// baseline (1008.066 us; speedup 1.0000x reference)
//
#include <hip/hip_runtime.h>
#include <stdint.h>

// ---------------------------------------------------------------------------
// RPN FPN head, MI355X (gfx950).
// conv3x3(256->512)+ReLU as implicit GEMM (bf16 MFMA 16x16x32, m97 structure),
// fused 1x1 heads (18 outputs) via small MFMA + atomicAdd partials,
// finalize kernel does biases + paired softmax + output scatter.
//
// Workspace layout (bytes):
//   [0,        2359296)   Wr2  bf16 [512 o][2304 k]   (B^T conv weights, k=(kh,kw,c))
//   [2359296,  2392064)   Wh2  bf16 [32 j][512 o]     (cls rows 0..5, box rows 6..17, rest 0)
//   [2392064, 17100800)   sbuf f32  [204288 slot][18] (head partial sums)
//   [17100800,123197440)  fpad bf16 padded NHWC feats (+128-px guard gaps)
// ---------------------------------------------------------------------------

typedef __bf16 bf16x8 __attribute__((ext_vector_type(8)));
typedef float  f32x4  __attribute__((ext_vector_type(4)));

#define WS_WR2_OFF   0
#define WS_WH2_OFF   2359296
#define WS_SB_OFF    2392064
#define WS_FP_OFF    17100800
#define WS_TOTAL     123197440

__device__ __forceinline__ unsigned short f2bf(float f) {
    unsigned u = __builtin_bit_cast(unsigned, f);
    unsigned r = (u + 0x7FFF + ((u >> 16) & 1)) >> 16;
    return (unsigned short)r;
}

__device__ __forceinline__ void gl_lds16(const void* g, void* l) {
    __builtin_amdgcn_global_load_lds(
        (const __attribute__((address_space(1))) unsigned int*)g,
        (__attribute__((address_space(3))) unsigned int*)l, 16, 0, 0);
}

// ---------------------------------------------------------------------------
// Kernel 1: weight repack.  Wr2[o*2304 + (r*256+c)] = bf16(W_conv[o][c][kh][kw]),
// r = kh*3+kw.  Wh2[j*512+o] = cls (j<6) / box (6<=j<18).
// ---------------------------------------------------------------------------
__global__ __launch_bounds__(256) void prep_weights(
    const float* __restrict__ Wc, const float* __restrict__ Wcls,
    const float* __restrict__ Wbox,
    unsigned short* __restrict__ wr2, unsigned short* __restrict__ wh2)
{
    int idx = blockIdx.x * 256 + threadIdx.x;
    if (idx < 1179648) {
        int o = idx / 2304;
        int k = idx - o * 2304;
        int r = k >> 8, c = k & 255;
        wr2[idx] = f2bf(Wc[o * 2304 + c * 9 + r]);
    } else {
        int i2 = idx - 1179648;
        if (i2 < 9216) {
            int j = i2 >> 9, o = i2 & 511;
            float v = (j < 6) ? Wcls[j * 512 + o] : Wbox[(j - 6) * 512 + o];
            wh2[j * 512 + o] = f2bf(v);
        }
    }
}

// ---------------------------------------------------------------------------
// Kernel 2: feature cast/transpose NCHW f32 -> padded NHWC bf16.
// One block per (b, level, h, 64-wide w-block); thread t: w = t&63, c-octet (t>>6).
// Pads/gaps stay zero from the memset.
// ---------------------------------------------------------------------------
__global__ __launch_bounds__(256) void prep_feats(
    const float* __restrict__ f0, const float* __restrict__ f1,
    const float* __restrict__ f2, const float* __restrict__ f3,
    const float* __restrict__ f4, unsigned short* __restrict__ fpad)
{
    int bi = blockIdx.x;            // < 3268
    int b = bi / 817;
    int r = bi - b * 817;
    const float* fsrc; int H, W, Wp, h, wb; long lb;
    if (r < 600)      { fsrc=f0; H=150; W=250; Wp=252; h=r>>1>>1; wb=r&3; lb=32768    + (long)b*9805824; h=r>>2; }
    else if (r < 750) { int rr=r-600; fsrc=f1; H=75; W=125; Wp=127; h=rr>>1; wb=rr&1; lb=39288832 + (long)b*2503424; }
    else if (r < 788) { fsrc=f2; H=38; W=63; Wp=65; h=r-750; wb=0; lb=49335296 + (long)b*665600; }
    else if (r < 807) { fsrc=f3; H=19; W=32; Wp=34; h=r-788; wb=0; lb=52030464 + (long)b*182784; }
    else              { fsrc=f4; H=10; W=16; Wp=18; h=r-807; wb=0; lb=52794368 + (long)b*55296; }
    int tid = threadIdx.x;
    int w = (tid & 63) + wb * 64;
    if (w >= W) return;
    const long cstr = (long)H * W;
    const float* src = fsrc + (((long)b * 256) * H + h) * W + w;
    unsigned short* dst = fpad + lb + (long)((h + 1) * Wp + (w + 1)) * 256;
    int cg = (tid >> 6) * 8;
    #pragma unroll
    for (int iter = 0; iter < 8; ++iter) {
        int c0 = cg + iter * 32;
        union { unsigned short u[8]; uint4 v; } pk;
        #pragma unroll
        for (int i = 0; i < 8; ++i) pk.u[i] = f2bf(src[(long)(c0 + i) * cstr]);
        *(uint4*)(dst + c0) = pk.v;
    }
}

// ---------------------------------------------------------------------------
// Kernel 3: main implicit-GEMM conv + fused head projection.
// Grid 6384 = 1596 M-tiles x 4 o-chunks. 256 thr, 4 waves, WG tile 128x128,
// wave tile 64x64 (16x16x32 bf16 MFMA), BK=64, global_load_lds width 16.
// ---------------------------------------------------------------------------
__global__ __launch_bounds__(256) void conv_main(
    const unsigned short* __restrict__ fpad,
    const unsigned short* __restrict__ wr2,
    const unsigned short* __restrict__ wh2,
    const float* __restrict__ b_conv,
    float* __restrict__ sbuf)
{
    __shared__ unsigned short smem[16384];   // A: [0,8192) ush, B: [8192,16384) ush
    const int tid = threadIdx.x;
    const int bx = blockIdx.x;
    const int tile = bx >> 2, chunk = bx & 3;
    int b = tile / 399;
    int tr = tile - b * 399;
    int Wp, lt; long lb;
    if (tr < 296)      { lt = tr;       Wp = 252; lb = 32768    + (long)b * 9805824; }
    else if (tr < 371) { lt = tr - 296; Wp = 127; lb = 39288832 + (long)b * 2503424; }
    else if (tr < 391) { lt = tr - 371; Wp = 65;  lb = 49335296 + (long)b * 665600;  }
    else if (tr < 397) { lt = tr - 391; Wp = 34;  lb = 52030464 + (long)b * 182784;  }
    else               { lt = tr - 397; Wp = 18;  lb = 52794368 + (long)b * 55296;   }

    const int arow  = tid >> 3;           // 0..31 (staging row group)
    const int alane = tid & 7;            // 16B slot within 64-elem row
    const long apix = lb + (long)(Wp + lt * 128 + arow) * 256 + alane * 8;
    const long bofs = (long)(chunk * 128 + arow) * 2304 + alane * 8;

    const int wv = tid >> 6, lane = tid & 63;
    char* lA = (char*)smem + wv * 1024;
    char* lB = (char*)smem + 16384 + wv * 1024;
    const int mrow = (wv & 1) * 64, ncol = (wv >> 1) * 64;
    const int mr = lane & 15;
    const int kq = (lane >> 4) * 8;

    f32x4 acc[4][4];
    #pragma unroll
    for (int mt = 0; mt < 4; ++mt)
        #pragma unroll
        for (int nt = 0; nt < 4; ++nt) acc[mt][nt] = (f32x4){0.f, 0.f, 0.f, 0.f};

    for (int r = 0; r < 9; ++r) {
        const int doff = (r / 3 - 1) * Wp + (r % 3 - 1);
        const unsigned short* ga = fpad + apix + (long)doff * 256;
        const unsigned short* gb = wr2 + bofs + r * 256;
        for (int cb = 0; cb < 4; ++cb) {
            const unsigned short* ga2 = ga + cb * 64;
            const unsigned short* gb2 = gb + cb * 64;
            #pragma unroll
            for (int i = 0; i < 4; ++i) {
                gl_lds16(ga2 + i * 8192,  lA + i * 4096);   // +32 pixel rows
                gl_lds16(gb2 + i * 73728, lB + i * 4096);   // +32 o rows
            }
            __syncthreads();
            #pragma unroll
            for (int kk = 0; kk < 64; kk += 32) {
                bf16x8 af[4], bfr[4];
                #pragma unroll
                for (int mt = 0; mt < 4; ++mt)
                    af[mt] = *(const bf16x8*)&smem[(mrow + mt * 16 + mr) * 64 + kk + kq];
                #pragma unroll
                for (int nt = 0; nt < 4; ++nt)
                    bfr[nt] = *(const bf16x8*)&smem[8192 + (ncol + nt * 16 + mr) * 64 + kk + kq];
                #pragma unroll
                for (int mt = 0; mt < 4; ++mt)
                    #pragma unroll
                    for (int nt = 0; nt < 4; ++nt)
                        acc[mt][nt] = __builtin_amdgcn_mfma_f32_16x16x32_bf16(
                            af[mt], bfr[nt], acc[mt][nt], 0, 0, 0);
            }
            __syncthreads();
        }
    }

    // Epilogue: bias + relu, conv1 -> LDS bf16 [128 px][128 o]
    float bias[4];
    #pragma unroll
    for (int nt = 0; nt < 4; ++nt) bias[nt] = b_conv[chunk * 128 + ncol + nt * 16 + mr];
    #pragma unroll
    for (int mt = 0; mt < 4; ++mt)
        #pragma unroll
        for (int nt = 0; nt < 4; ++nt)
            #pragma unroll
            for (int q = 0; q < 4; ++q) {
                int row = mrow + mt * 16 + (lane >> 4) * 4 + q;
                int col = ncol + nt * 16 + mr;
                smem[row * 128 + col] = f2bf(fmaxf(acc[mt][nt][q] + bias[nt], 0.0f));
            }
    __syncthreads();

    // Head GEMM: [128 px x 128 o] @ Wh2^T chunk -> [128 px x 32 j]
    f32x4 acc2[2][2];
    #pragma unroll
    for (int mi = 0; mi < 2; ++mi)
        #pragma unroll
        for (int ni = 0; ni < 2; ++ni) acc2[mi][ni] = (f32x4){0.f, 0.f, 0.f, 0.f};
    #pragma unroll
    for (int ks = 0; ks < 4; ++ks) {
        bf16x8 ha[2], hb[2];
        #pragma unroll
        for (int mi = 0; mi < 2; ++mi)
            ha[mi] = *(const bf16x8*)&smem[((wv * 2 + mi) * 16 + mr) * 128 + ks * 32 + kq];
        #pragma unroll
        for (int ni = 0; ni < 2; ++ni)
            hb[ni] = *(const bf16x8*)&wh2[(ni * 16 + mr) * 512 + chunk * 128 + ks * 32 + kq];
        #pragma unroll
        for (int mi = 0; mi < 2; ++mi)
            #pragma unroll
            for (int ni = 0; ni < 2; ++ni)
                acc2[mi][ni] = __builtin_amdgcn_mfma_f32_16x16x32_bf16(
                    ha[mi], hb[ni], acc2[mi][ni], 0, 0, 0);
    }
    const long slotbase = (long)tile * 128;
    #pragma unroll
    for (int ni = 0; ni < 2; ++ni) {
        int j = ni * 16 + mr;
        if (j < 18) {
            #pragma unroll
            for (int mi = 0; mi < 2; ++mi)
                #pragma unroll
                for (int q = 0; q < 4; ++q) {
                    int row = (wv * 2 + mi) * 16 + (lane >> 4) * 4 + q;
                    atomicAdd(&sbuf[(slotbase + row) * 18 + j], acc2[mi][ni][q]);
                }
        }
    }
}

// ---------------------------------------------------------------------------
// Kernel 4: finalize. slot -> (b,level,hp,wp); biases, paired sigmoid-softmax
// (partner = c +/- 3), scatter into the 3 concatenated outputs.
// ---------------------------------------------------------------------------
__global__ __launch_bounds__(256) void finalize(
    const float* __restrict__ sbuf, const float* __restrict__ b_cls,
    const float* __restrict__ b_box, float* __restrict__ out)
{
    int idx = blockIdx.x * 256 + threadIdx.x;      // < 204288
    int tile = idx >> 7, m = idx & 127;
    int b = tile / 399;
    int tr = tile - b * 399;
    int hp, wp, H, W, noff;
    if (tr < 296)      { int f = 252 + (tr)       * 128 + m; hp = f / 252; wp = f - hp * 252; H = 150; W = 250; noff = 0; }
    else if (tr < 371) { int f = 127 + (tr - 296) * 128 + m; hp = f / 127; wp = f - hp * 127; H = 75;  W = 125; noff = 112500; }
    else if (tr < 391) { int f = 65  + (tr - 371) * 128 + m; hp = f / 65;  wp = f - hp * 65;  H = 38;  W = 63;  noff = 140625; }
    else if (tr < 397) { int f = 34  + (tr - 391) * 128 + m; hp = f / 34;  wp = f - hp * 34;  H = 19;  W = 32;  noff = 147807; }
    else               { int f = 18  + (tr - 397) * 128 + m; hp = f / 18;  wp = f - hp * 18;  H = 10;  W = 16;  noff = 149631; }
    if (hp < 1 || hp > H || wp < 1 || wp > W) return;

    const float* s = sbuf + (long)idx * 18;
    float sc[6], bb[12], pr[6];
    #pragma unroll
    for (int c = 0; c < 6; ++c) sc[c] = s[c] + b_cls[c];
    #pragma unroll
    for (int k = 0; k < 12; ++k) bb[k] = s[6 + k] + b_box[k];
    #pragma unroll
    for (int c = 0; c < 6; ++c) {
        int p = (c < 3) ? c + 3 : c - 3;
        pr[c] = 1.0f / (1.0f + expf(sc[p] - sc[c]));
    }
    int n = noff + ((hp - 1) * W + (wp - 1)) * 3;
    long o0 = ((long)b * 150111 + n) * 2;
    float* O0 = out + o0;
    float* O1 = out + 1200888 + o0;
    float* O2 = out + 2401776 + ((long)b * 150111 + n) * 4;
    #pragma unroll
    for (int c = 0; c < 6; ++c) { O0[c] = sc[c]; O1[c] = pr[c]; }
    #pragma unroll
    for (int k = 0; k < 12; ++k) O2[k] = bb[k];
}

// ---------------------------------------------------------------------------
extern "C" void kernel_launch(void* const* d_in, const int* in_sizes, int n_in,
                              void* d_out, int out_size, void* d_ws, size_t ws_size,
                              hipStream_t stream)
{
    const float* f0   = (const float*)d_in[0];
    const float* f1   = (const float*)d_in[1];
    const float* f2   = (const float*)d_in[2];
    const float* f3   = (const float*)d_in[3];
    const float* f4   = (const float*)d_in[4];
    // d_in[5] = im_info (unused by reference math)
    const float* Wc   = (const float*)d_in[6];
    const float* bC   = (const float*)d_in[7];
    const float* Wcls = (const float*)d_in[8];
    const float* bcls = (const float*)d_in[9];
    const float* Wbox = (const float*)d_in[10];
    const float* bbox = (const float*)d_in[11];

    unsigned short* wr2  = (unsigned short*)((char*)d_ws + WS_WR2_OFF);
    unsigned short* wh2  = (unsigned short*)((char*)d_ws + WS_WH2_OFF);
    float*          sbuf = (float*)((char*)d_ws + WS_SB_OFF);
    unsigned short* fpad = (unsigned short*)((char*)d_ws + WS_FP_OFF);

    hipMemsetAsync(d_ws, 0, (size_t)WS_TOTAL, stream);
    hipLaunchKernelGGL(prep_weights, dim3(4644), dim3(256), 0, stream, Wc, Wcls, Wbox, wr2, wh2);
    hipLaunchKernelGGL(prep_feats,   dim3(3268), dim3(256), 0, stream, f0, f1, f2, f3, f4, fpad);
    hipLaunchKernelGGL(conv_main,    dim3(6384), dim3(256), 0, stream, fpad, wr2, wh2, bC, sbuf);
    hipLaunchKernelGGL(finalize,     dim3(798),  dim3(256), 0, stream, sbuf, bcls, bbox, (float*)d_out);
}

// Round 2
// 892.181 us; speedup vs baseline: 1.1299x; 1.1299x over previous
//
#include <hip/hip_runtime.h>
#include <stdint.h>

// ---------------------------------------------------------------------------
// RPN FPN head, MI355X (gfx950).
// conv3x3(256->512)+ReLU as implicit GEMM (bf16 MFMA 16x16x32, m97 structure,
// XOR-swizzled LDS to kill 16-way ds_read_b128 bank conflicts),
// fused 1x1 heads (18 outputs) via small MFMA + atomicAdd partials,
// finalize kernel does biases + paired softmax + output scatter.
//
// Workspace layout (bytes):
//   [0,        2359296)   Wr2  bf16 [512 o][2304 k]   (B^T conv weights, k=(kh,kw,c))
//   [2359296,  2392064)   Wh2  bf16 [32 j][512 o]     (cls rows 0..5, box rows 6..17)
//   [2392064, 17100800)   sbuf f32  [204288 slot][18] (head partial sums)
//   [17100800,123197440)  fpad bf16 padded NHWC feats (+guard gaps)
// ---------------------------------------------------------------------------

typedef __bf16 bf16x8 __attribute__((ext_vector_type(8)));
typedef float  f32x4  __attribute__((ext_vector_type(4)));

#define WS_WR2_OFF   0
#define WS_WH2_OFF   2359296
#define WS_SB_OFF    2392064
#define WS_FP_OFF    17100800
#define WS_TOTAL     123197440

__device__ __forceinline__ unsigned short f2bf(float f) {
    unsigned u = __builtin_bit_cast(unsigned, f);
    unsigned r = (u + 0x7FFF + ((u >> 16) & 1)) >> 16;
    return (unsigned short)r;
}

__device__ __forceinline__ void gl_lds16(const void* g, void* l) {
    __builtin_amdgcn_global_load_lds(
        (const __attribute__((address_space(1))) unsigned int*)g,
        (__attribute__((address_space(3))) unsigned int*)l, 16, 0, 0);
}

// ---------------------------------------------------------------------------
// Kernel 1: weight repack.  Wr2[o*2304 + (r*256+c)] = bf16(W_conv[o][c][kh][kw]),
// r = kh*3+kw.  Wh2[j*512+o] = cls (j<6) / box (6<=j<18).
// ---------------------------------------------------------------------------
__global__ __launch_bounds__(256) void prep_weights(
    const float* __restrict__ Wc, const float* __restrict__ Wcls,
    const float* __restrict__ Wbox,
    unsigned short* __restrict__ wr2, unsigned short* __restrict__ wh2)
{
    int idx = blockIdx.x * 256 + threadIdx.x;
    if (idx < 1179648) {
        int o = idx / 2304;
        int k = idx - o * 2304;
        int r = k >> 8, c = k & 255;
        wr2[idx] = f2bf(Wc[o * 2304 + c * 9 + r]);
    } else {
        int i2 = idx - 1179648;
        if (i2 < 9216) {
            int j = i2 >> 9, o = i2 & 511;
            float v = (j < 6) ? Wcls[j * 512 + o] : Wbox[(j - 6) * 512 + o];
            wh2[j * 512 + o] = f2bf(v);
        }
    }
}

// ---------------------------------------------------------------------------
// Kernel 2: feature cast/transpose NCHW f32 -> padded NHWC bf16, via an LDS
// transpose tile so BOTH global reads and writes are coalesced.
// One block per (b, level, h, 64-wide w-block).
//  phase 1: lanes over w (coalesced f32 reads), pack bf16 pairs -> LDS[w][258]
//  phase 2: lanes over contiguous 16B chunks of the 64px*512B output strip.
// ---------------------------------------------------------------------------
__global__ __launch_bounds__(256) void prep_feats(
    const float* __restrict__ f0, const float* __restrict__ f1,
    const float* __restrict__ f2, const float* __restrict__ f3,
    const float* __restrict__ f4, unsigned short* __restrict__ fpad)
{
    __shared__ unsigned short lds[64 * 258];
    int bi = blockIdx.x;            // < 3268
    int b = bi / 817;
    int r = bi - b * 817;
    const float* fsrc; int H, W, Wp, h, wb; long lb;
    if (r < 600)      { fsrc=f0; H=150; W=250; Wp=252; h=r>>2; wb=r&3; lb=32768    + (long)b*9805824; }
    else if (r < 750) { int rr=r-600; fsrc=f1; H=75; W=125; Wp=127; h=rr>>1; wb=rr&1; lb=39288832 + (long)b*2503424; }
    else if (r < 788) { fsrc=f2; H=38; W=63; Wp=65; h=r-750; wb=0; lb=49335296 + (long)b*665600; }
    else if (r < 807) { fsrc=f3; H=19; W=32; Wp=34; h=r-788; wb=0; lb=52030464 + (long)b*182784; }
    else              { fsrc=f4; H=10; W=16; Wp=18; h=r-807; wb=0; lb=52794368 + (long)b*55296; }
    const int t = threadIdx.x;
    const long cstr = (long)H * W;
    const int w = t & 63;
    const int wg = wb * 64 + w;
    const bool wv = (wg < W);
    const float* src = fsrc + (((long)b * 256) * H + h) * W + wg;
    // phase 1: 32 iters, each thread packs one bf16 pair -> ds_write_b32
    unsigned* ldsw = (unsigned*)lds;
    #pragma unroll 4
    for (int it = 0; it < 32; ++it) {
        int c0 = (t >> 6) * 2 + it * 8;           // even c in [0,256)
        float v0 = wv ? src[(long)c0 * cstr] : 0.0f;
        float v1 = wv ? src[(long)(c0 + 1) * cstr] : 0.0f;
        unsigned pk = (unsigned)f2bf(v0) | ((unsigned)f2bf(v1) << 16);
        ldsw[w * 129 + (c0 >> 1)] = pk;
    }
    __syncthreads();
    // phase 2: 8 iters; chunk g = k*256 + t covers the 32KB strip contiguously
    #pragma unroll
    for (int k = 0; k < 8; ++k) {
        int g  = k * 256 + t;
        int px = g >> 5;                          // 0..63
        int pg = wb * 64 + px;
        if (pg >= W) continue;
        int d0 = px * 129 + (g & 31) * 4;         // dword index in lds
        uint4 v;
        v.x = ldsw[d0]; v.y = ldsw[d0 + 1]; v.z = ldsw[d0 + 2]; v.w = ldsw[d0 + 3];
        unsigned short* dst = fpad + lb + (long)((h + 1) * Wp + (pg + 1)) * 256 + (g & 31) * 8;
        *(uint4*)dst = v;
    }
}

// ---------------------------------------------------------------------------
// Kernel 3: main implicit-GEMM conv + fused head projection.
// Grid 6384 = 1596 M-tiles x 4 o-chunks. 256 thr, 4 waves, WG tile 128x128,
// wave tile 64x64 (16x16x32 bf16 MFMA), BK=64, global_load_lds width 16.
// LDS K-slots XOR-swizzled by (row&7): staging lane fetches global slot
// (lane&7)^(row&7); reader of logical slot s reads s^(row&7). Keeps
// ds_read_b128 16B-aligned while spreading the 16 mr-lanes over 32 banks.
// ---------------------------------------------------------------------------
__global__ __launch_bounds__(256) void conv_main(
    const unsigned short* __restrict__ fpad,
    const unsigned short* __restrict__ wr2,
    const unsigned short* __restrict__ wh2,
    const float* __restrict__ b_conv,
    float* __restrict__ sbuf)
{
    __shared__ unsigned short smem[16384];   // A: [0,8192) ush, B: [8192,16384) ush
    const int tid = threadIdx.x;
    const int bx = blockIdx.x;
    const int tile = bx >> 2, chunk = bx & 3;
    int b = tile / 399;
    int tr = tile - b * 399;
    int Wp, lt; long lb;
    if (tr < 296)      { lt = tr;       Wp = 252; lb = 32768    + (long)b * 9805824; }
    else if (tr < 371) { lt = tr - 296; Wp = 127; lb = 39288832 + (long)b * 2503424; }
    else if (tr < 391) { lt = tr - 371; Wp = 65;  lb = 49335296 + (long)b * 665600;  }
    else if (tr < 397) { lt = tr - 391; Wp = 34;  lb = 52030464 + (long)b * 182784;  }
    else               { lt = tr - 397; Wp = 18;  lb = 52794368 + (long)b * 55296;   }

    const int arow  = tid >> 3;                       // 0..31 staging row group
    const int aslot = (tid & 7) ^ (arow & 7);         // swizzled global 16B slot
    const long apix = lb + (long)(Wp + lt * 128 + arow) * 256 + aslot * 8;
    const long bofs = (long)(chunk * 128 + arow) * 2304 + aslot * 8;

    const int wv = tid >> 6, lane = tid & 63;
    char* lA = (char*)smem + wv * 1024;
    char* lB = (char*)smem + 16384 + wv * 1024;
    const int mrow = (wv & 1) * 64, ncol = (wv >> 1) * 64;
    const int mr = lane & 15;
    const int kq = (lane >> 4) * 8;
    const int m7 = mr & 7;                            // == row&7 for all frag rows

    f32x4 acc[4][4];
    #pragma unroll
    for (int mt = 0; mt < 4; ++mt)
        #pragma unroll
        for (int nt = 0; nt < 4; ++nt) acc[mt][nt] = (f32x4){0.f, 0.f, 0.f, 0.f};

    for (int r = 0; r < 9; ++r) {
        const int doff = (r / 3 - 1) * Wp + (r % 3 - 1);
        const unsigned short* ga = fpad + apix + (long)doff * 256;
        const unsigned short* gb = wr2 + bofs + r * 256;
        for (int cb = 0; cb < 4; ++cb) {
            const unsigned short* ga2 = ga + cb * 64;
            const unsigned short* gb2 = gb + cb * 64;
            #pragma unroll
            for (int i = 0; i < 4; ++i) {
                gl_lds16(ga2 + i * 8192,  lA + i * 4096);   // +32 pixel rows
                gl_lds16(gb2 + i * 73728, lB + i * 4096);   // +32 o rows
            }
            __syncthreads();
            #pragma unroll
            for (int kk = 0; kk < 64; kk += 32) {
                const int sx = ((((kk >> 3) + (lane >> 4)) ^ m7) << 3);
                bf16x8 af[4], bfr[4];
                #pragma unroll
                for (int mt = 0; mt < 4; ++mt)
                    af[mt] = *(const bf16x8*)&smem[(mrow + mt * 16 + mr) * 64 + sx];
                #pragma unroll
                for (int nt = 0; nt < 4; ++nt)
                    bfr[nt] = *(const bf16x8*)&smem[8192 + (ncol + nt * 16 + mr) * 64 + sx];
                #pragma unroll
                for (int mt = 0; mt < 4; ++mt)
                    #pragma unroll
                    for (int nt = 0; nt < 4; ++nt)
                        acc[mt][nt] = __builtin_amdgcn_mfma_f32_16x16x32_bf16(
                            af[mt], bfr[nt], acc[mt][nt], 0, 0, 0);
            }
            __syncthreads();
        }
    }

    // Epilogue: bias + relu, conv1 -> LDS bf16 [128 px][128 o], same XOR swizzle
    float bias[4];
    #pragma unroll
    for (int nt = 0; nt < 4; ++nt) bias[nt] = b_conv[chunk * 128 + ncol + nt * 16 + mr];
    #pragma unroll
    for (int mt = 0; mt < 4; ++mt)
        #pragma unroll
        for (int nt = 0; nt < 4; ++nt)
            #pragma unroll
            for (int q = 0; q < 4; ++q) {
                int row = mrow + mt * 16 + (lane >> 4) * 4 + q;
                int col = ncol + nt * 16 + mr;
                int sl  = (col >> 3) ^ (row & 7);
                smem[row * 128 + (sl << 3) + (col & 7)] =
                    f2bf(fmaxf(acc[mt][nt][q] + bias[nt], 0.0f));
            }
    __syncthreads();

    // Head GEMM: [128 px x 128 o] @ Wh2^T chunk -> [128 px x 32 j]
    f32x4 acc2[2][2];
    #pragma unroll
    for (int mi = 0; mi < 2; ++mi)
        #pragma unroll
        for (int ni = 0; ni < 2; ++ni) acc2[mi][ni] = (f32x4){0.f, 0.f, 0.f, 0.f};
    #pragma unroll
    for (int ks = 0; ks < 4; ++ks) {
        const int sg = ks * 4 + (lane >> 4);          // logical 16B slot 0..15
        bf16x8 ha[2], hb[2];
        #pragma unroll
        for (int mi = 0; mi < 2; ++mi) {
            int rowH = (wv * 2 + mi) * 16 + mr;
            ha[mi] = *(const bf16x8*)&smem[rowH * 128 + ((sg ^ m7) << 3)];
        }
        #pragma unroll
        for (int ni = 0; ni < 2; ++ni)
            hb[ni] = *(const bf16x8*)&wh2[(ni * 16 + mr) * 512 + chunk * 128 + ks * 32 + kq];
        #pragma unroll
        for (int mi = 0; mi < 2; ++mi)
            #pragma unroll
            for (int ni = 0; ni < 2; ++ni)
                acc2[mi][ni] = __builtin_amdgcn_mfma_f32_16x16x32_bf16(
                    ha[mi], hb[ni], acc2[mi][ni], 0, 0, 0);
    }
    const long slotbase = (long)tile * 128;
    #pragma unroll
    for (int ni = 0; ni < 2; ++ni) {
        int j = ni * 16 + mr;
        if (j < 18) {
            #pragma unroll
            for (int mi = 0; mi < 2; ++mi)
                #pragma unroll
                for (int q = 0; q < 4; ++q) {
                    int row = (wv * 2 + mi) * 16 + (lane >> 4) * 4 + q;
                    atomicAdd(&sbuf[(slotbase + row) * 18 + j], acc2[mi][ni][q]);
                }
        }
    }
}

// ---------------------------------------------------------------------------
// Kernel 4: finalize. slot -> (b,level,hp,wp); biases, paired sigmoid-softmax
// (partner = c +/- 3), scatter into the 3 concatenated outputs.
// ---------------------------------------------------------------------------
__global__ __launch_bounds__(256) void finalize(
    const float* __restrict__ sbuf, const float* __restrict__ b_cls,
    const float* __restrict__ b_box, float* __restrict__ out)
{
    int idx = blockIdx.x * 256 + threadIdx.x;      // < 204288
    int tile = idx >> 7, m = idx & 127;
    int b = tile / 399;
    int tr = tile - b * 399;
    int hp, wp, H, W, noff;
    if (tr < 296)      { int f = 252 + (tr)       * 128 + m; hp = f / 252; wp = f - hp * 252; H = 150; W = 250; noff = 0; }
    else if (tr < 371) { int f = 127 + (tr - 296) * 128 + m; hp = f / 127; wp = f - hp * 127; H = 75;  W = 125; noff = 112500; }
    else if (tr < 391) { int f = 65  + (tr - 371) * 128 + m; hp = f / 65;  wp = f - hp * 65;  H = 38;  W = 63;  noff = 140625; }
    else if (tr < 397) { int f = 34  + (tr - 391) * 128 + m; hp = f / 34;  wp = f - hp * 34;  H = 19;  W = 32;  noff = 147807; }
    else               { int f = 18  + (tr - 397) * 128 + m; hp = f / 18;  wp = f - hp * 18;  H = 10;  W = 16;  noff = 149631; }
    if (hp < 1 || hp > H || wp < 1 || wp > W) return;

    const float* s = sbuf + (long)idx * 18;
    float sc[6], bb[12], pr[6];
    #pragma unroll
    for (int c = 0; c < 6; ++c) sc[c] = s[c] + b_cls[c];
    #pragma unroll
    for (int k = 0; k < 12; ++k) bb[k] = s[6 + k] + b_box[k];
    #pragma unroll
    for (int c = 0; c < 6; ++c) {
        int p = (c < 3) ? c + 3 : c - 3;
        pr[c] = 1.0f / (1.0f + expf(sc[p] - sc[c]));
    }
    int n = noff + ((hp - 1) * W + (wp - 1)) * 3;
    long o0 = ((long)b * 150111 + n) * 2;
    float* O0 = out + o0;
    float* O1 = out + 1200888 + o0;
    float* O2 = out + 2401776 + ((long)b * 150111 + n) * 4;
    #pragma unroll
    for (int c = 0; c < 6; ++c) { O0[c] = sc[c]; O1[c] = pr[c]; }
    #pragma unroll
    for (int k = 0; k < 12; ++k) O2[k] = bb[k];
}

// ---------------------------------------------------------------------------
extern "C" void kernel_launch(void* const* d_in, const int* in_sizes, int n_in,
                              void* d_out, int out_size, void* d_ws, size_t ws_size,
                              hipStream_t stream)
{
    const float* f0   = (const float*)d_in[0];
    const float* f1   = (const float*)d_in[1];
    const float* f2   = (const float*)d_in[2];
    const float* f3   = (const float*)d_in[3];
    const float* f4   = (const float*)d_in[4];
    // d_in[5] = im_info (unused by reference math)
    const float* Wc   = (const float*)d_in[6];
    const float* bC   = (const float*)d_in[7];
    const float* Wcls = (const float*)d_in[8];
    const float* bcls = (const float*)d_in[9];
    const float* Wbox = (const float*)d_in[10];
    const float* bbox = (const float*)d_in[11];

    unsigned short* wr2  = (unsigned short*)((char*)d_ws + WS_WR2_OFF);
    unsigned short* wh2  = (unsigned short*)((char*)d_ws + WS_WH2_OFF);
    float*          sbuf = (float*)((char*)d_ws + WS_SB_OFF);
    unsigned short* fpad = (unsigned short*)((char*)d_ws + WS_FP_OFF);

    hipMemsetAsync(d_ws, 0, (size_t)WS_TOTAL, stream);
    hipLaunchKernelGGL(prep_weights, dim3(4644), dim3(256), 0, stream, Wc, Wcls, Wbox, wr2, wh2);
    hipLaunchKernelGGL(prep_feats,   dim3(3268), dim3(256), 0, stream, f0, f1, f2, f3, f4, fpad);
    hipLaunchKernelGGL(conv_main,    dim3(6384), dim3(256), 0, stream, fpad, wr2, wh2, bC, sbuf);
    hipLaunchKernelGGL(finalize,     dim3(798),  dim3(256), 0, stream, sbuf, bcls, bbox, (float*)d_out);
}

// Round 3
// 886.073 us; speedup vs baseline: 1.1377x; 1.0069x over previous
//
#include <hip/hip_runtime.h>
#include <stdint.h>

// ---------------------------------------------------------------------------
// RPN FPN head, MI355X (gfx950).
// conv3x3(256->512)+ReLU as implicit GEMM (bf16 MFMA 16x16x32, m97 structure,
// XOR-swizzled LDS, XCD-swizzled grid), fused 1x1 heads via small MFMA +
// atomicAdd partials, finalize does biases + paired softmax + scatter.
//
// Workspace layout (bytes):
//   [0,        2359296)   Wr2  bf16 [512 o][2304 k]   (B^T conv weights, k=(kh,kw,c))
//   [2359296,  2392064)   Wh2  bf16 [32 j][512 o]     (cls 0..5, box 6..17, 18..31 zero)
//   [2392064, 17100800)   sbuf f32  [204288 slot][18] (head partial sums; memset 0)
//   [17100800,123197440)  fpad bf16 padded NHWC feats (only pad RINGS zeroed;
//                         guard/overrun cells may hold poison -> outputs discarded)
// ---------------------------------------------------------------------------

typedef __bf16 bf16x8 __attribute__((ext_vector_type(8)));
typedef float  f32x4  __attribute__((ext_vector_type(4)));

#define WS_WR2_OFF   0
#define WS_WH2_OFF   2359296
#define WS_SB_OFF    2392064
#define WS_FP_OFF    17100800
#define WS_TOTAL     123197440

__device__ __forceinline__ unsigned short f2bf(float f) {
    unsigned u = __builtin_bit_cast(unsigned, f);
    unsigned r = (u + 0x7FFF + ((u >> 16) & 1)) >> 16;
    return (unsigned short)r;
}

__device__ __forceinline__ void gl_lds16(const void* g, void* l) {
    __builtin_amdgcn_global_load_lds(
        (const __attribute__((address_space(1))) unsigned int*)g,
        (__attribute__((address_space(3))) unsigned int*)l, 16, 0, 0);
}

// ---------------------------------------------------------------------------
// Kernel 1: weight repack.  Wr2[o*2304 + (r*256+c)] = bf16(W_conv[o][c][kh][kw]),
// r = kh*3+kw.  Wh2[j*512+o] = cls (j<6) / box (6<=j<18) / 0 (18<=j<32).
// ---------------------------------------------------------------------------
__global__ __launch_bounds__(256) void prep_weights(
    const float* __restrict__ Wc, const float* __restrict__ Wcls,
    const float* __restrict__ Wbox,
    unsigned short* __restrict__ wr2, unsigned short* __restrict__ wh2)
{
    int idx = blockIdx.x * 256 + threadIdx.x;
    if (idx < 1179648) {
        int o = idx / 2304;
        int k = idx - o * 2304;
        int r = k >> 8, c = k & 255;
        wr2[idx] = f2bf(Wc[o * 2304 + c * 9 + r]);
    } else {
        int i2 = idx - 1179648;
        if (i2 < 16384) {
            int j = i2 >> 9, o = i2 & 511;
            float v = (j < 6) ? Wcls[j * 512 + o]
                    : (j < 18) ? Wbox[(j - 6) * 512 + o] : 0.0f;
            wh2[j * 512 + o] = f2bf(v);
        }
    }
}

// ---------------------------------------------------------------------------
// Kernel 1b: zero the SAME-padding rings of each (b, level) padded image.
// Only these cells feed conv outputs that finalize keeps; interior is fully
// overwritten by prep_feats, guard/overrun cells feed discarded outputs.
// 201728 threads: idx -> (b, level, ring-cell c, 16B slot).
// ---------------------------------------------------------------------------
__global__ __launch_bounds__(256) void zero_rings(unsigned short* __restrict__ fpad)
{
    int idx = blockIdx.x * 256 + threadIdx.x;        // < 201728 = 4 * 50432
    int b = idx / 50432;
    int rem = idx - b * 50432;
    int Wp, H, W; long lb;
    if (rem < 25728)      {               Wp=252; H=150; W=250; lb=32768    + (long)b*9805824; }
    else if (rem < 38656) { rem -= 25728; Wp=127; H=75;  W=125; lb=39288832 + (long)b*2503424; }
    else if (rem < 45248) { rem -= 38656; Wp=65;  H=38;  W=63;  lb=49335296 + (long)b*665600;  }
    else if (rem < 48640) { rem -= 45248; Wp=34;  H=19;  W=32;  lb=52030464 + (long)b*182784;  }
    else                  { rem -= 48640; Wp=18;  H=10;  W=16;  lb=52794368 + (long)b*55296;   }
    int c = rem >> 5, slot = rem & 31;
    int h, w;
    if (c < Wp)          { h = 0;     w = c; }
    else if (c < 2 * Wp) { h = H + 1; w = c - Wp; }
    else {
        int c2 = c - 2 * Wp;
        h = 1 + (c2 >> 1);
        w = (c2 & 1) ? (W + 1) : 0;
    }
    uint4 z = {0u, 0u, 0u, 0u};
    *(uint4*)(fpad + lb + (long)(h * Wp + w) * 256 + slot * 8) = z;
}

// ---------------------------------------------------------------------------
// Kernel 2: feature cast/transpose NCHW f32 -> padded NHWC bf16, via an LDS
// transpose tile so BOTH global reads and writes are coalesced.
// ---------------------------------------------------------------------------
__global__ __launch_bounds__(256) void prep_feats(
    const float* __restrict__ f0, const float* __restrict__ f1,
    const float* __restrict__ f2, const float* __restrict__ f3,
    const float* __restrict__ f4, unsigned short* __restrict__ fpad)
{
    __shared__ unsigned short lds[64 * 258];
    int bi = blockIdx.x;            // < 3268
    int b = bi / 817;
    int r = bi - b * 817;
    const float* fsrc; int H, W, Wp, h, wb; long lb;
    if (r < 600)      { fsrc=f0; H=150; W=250; Wp=252; h=r>>2; wb=r&3; lb=32768    + (long)b*9805824; }
    else if (r < 750) { int rr=r-600; fsrc=f1; H=75; W=125; Wp=127; h=rr>>1; wb=rr&1; lb=39288832 + (long)b*2503424; }
    else if (r < 788) { fsrc=f2; H=38; W=63; Wp=65; h=r-750; wb=0; lb=49335296 + (long)b*665600; }
    else if (r < 807) { fsrc=f3; H=19; W=32; Wp=34; h=r-788; wb=0; lb=52030464 + (long)b*182784; }
    else              { fsrc=f4; H=10; W=16; Wp=18; h=r-807; wb=0; lb=52794368 + (long)b*55296; }
    const int t = threadIdx.x;
    const long cstr = (long)H * W;
    const int w = t & 63;
    const int wg = wb * 64 + w;
    const bool wv = (wg < W);
    const float* src = fsrc + (((long)b * 256) * H + h) * W + wg;
    unsigned* ldsw = (unsigned*)lds;
    #pragma unroll 4
    for (int it = 0; it < 32; ++it) {
        int c0 = (t >> 6) * 2 + it * 8;           // even c in [0,256)
        float v0 = wv ? src[(long)c0 * cstr] : 0.0f;
        float v1 = wv ? src[(long)(c0 + 1) * cstr] : 0.0f;
        unsigned pk = (unsigned)f2bf(v0) | ((unsigned)f2bf(v1) << 16);
        ldsw[w * 129 + (c0 >> 1)] = pk;
    }
    __syncthreads();
    #pragma unroll
    for (int k = 0; k < 8; ++k) {
        int g  = k * 256 + t;
        int px = g >> 5;                          // 0..63
        int pg = wb * 64 + px;
        if (pg >= W) continue;
        int d0 = px * 129 + (g & 31) * 4;         // dword index in lds
        uint4 v;
        v.x = ldsw[d0]; v.y = ldsw[d0 + 1]; v.z = ldsw[d0 + 2]; v.w = ldsw[d0 + 3];
        unsigned short* dst = fpad + lb + (long)((h + 1) * Wp + (pg + 1)) * 256 + (g & 31) * 8;
        *(uint4*)dst = v;
    }
}

// ---------------------------------------------------------------------------
// Kernel 3: main implicit-GEMM conv + fused head projection.
// Grid 6400 (16 idle): XCD swizzle tile=(bid>>5)*8+(bid&7), chunk=(bid>>3)&3
// so a tile's 4 chunk-blocks share bid%8 (same XCD) -> A-tile L2-resident.
// 256 thr, 4 waves, WG tile 128x128, wave 64x64 (16x16x32 bf16 MFMA), BK=64,
// global_load_lds width 16, XOR-swizzled LDS K-slots (conflict-free b128).
// ---------------------------------------------------------------------------
__global__ __launch_bounds__(256) void conv_main(
    const unsigned short* __restrict__ fpad,
    const unsigned short* __restrict__ wr2,
    const unsigned short* __restrict__ wh2,
    const float* __restrict__ b_conv,
    float* __restrict__ sbuf)
{
    __shared__ unsigned short smem[16384];   // A: [0,8192) ush, B: [8192,16384) ush
    const int tid = threadIdx.x;
    const int bid = blockIdx.x;
    const int tile = ((bid >> 5) << 3) + (bid & 7);
    const int chunk = (bid >> 3) & 3;
    if (tile >= 1596) return;
    int b = tile / 399;
    int tr = tile - b * 399;
    int Wp, lt; long lb;
    if (tr < 296)      { lt = tr;       Wp = 252; lb = 32768    + (long)b * 9805824; }
    else if (tr < 371) { lt = tr - 296; Wp = 127; lb = 39288832 + (long)b * 2503424; }
    else if (tr < 391) { lt = tr - 371; Wp = 65;  lb = 49335296 + (long)b * 665600;  }
    else if (tr < 397) { lt = tr - 391; Wp = 34;  lb = 52030464 + (long)b * 182784;  }
    else               { lt = tr - 397; Wp = 18;  lb = 52794368 + (long)b * 55296;   }

    const int arow  = tid >> 3;                       // 0..31 staging row group
    const int aslot = (tid & 7) ^ (arow & 7);         // swizzled global 16B slot
    const long apix = lb + (long)(Wp + lt * 128 + arow) * 256 + aslot * 8;
    const long bofs = (long)(chunk * 128 + arow) * 2304 + aslot * 8;

    const int wv = tid >> 6, lane = tid & 63;
    char* lA = (char*)smem + wv * 1024;
    char* lB = (char*)smem + 16384 + wv * 1024;
    const int mrow = (wv & 1) * 64, ncol = (wv >> 1) * 64;
    const int mr = lane & 15;
    const int kq = (lane >> 4) * 8;
    const int m7 = mr & 7;                            // == row&7 for all frag rows

    f32x4 acc[4][4];
    #pragma unroll
    for (int mt = 0; mt < 4; ++mt)
        #pragma unroll
        for (int nt = 0; nt < 4; ++nt) acc[mt][nt] = (f32x4){0.f, 0.f, 0.f, 0.f};

    for (int r = 0; r < 9; ++r) {
        const int doff = (r / 3 - 1) * Wp + (r % 3 - 1);
        const unsigned short* ga = fpad + apix + (long)doff * 256;
        const unsigned short* gb = wr2 + bofs + r * 256;
        for (int cb = 0; cb < 4; ++cb) {
            const unsigned short* ga2 = ga + cb * 64;
            const unsigned short* gb2 = gb + cb * 64;
            #pragma unroll
            for (int i = 0; i < 4; ++i) {
                gl_lds16(ga2 + i * 8192,  lA + i * 4096);   // +32 pixel rows
                gl_lds16(gb2 + i * 73728, lB + i * 4096);   // +32 o rows
            }
            __syncthreads();
            #pragma unroll
            for (int kk = 0; kk < 64; kk += 32) {
                const int sx = ((((kk >> 3) + (lane >> 4)) ^ m7) << 3);
                bf16x8 af[4], bfr[4];
                #pragma unroll
                for (int mt = 0; mt < 4; ++mt)
                    af[mt] = *(const bf16x8*)&smem[(mrow + mt * 16 + mr) * 64 + sx];
                #pragma unroll
                for (int nt = 0; nt < 4; ++nt)
                    bfr[nt] = *(const bf16x8*)&smem[8192 + (ncol + nt * 16 + mr) * 64 + sx];
                #pragma unroll
                for (int mt = 0; mt < 4; ++mt)
                    #pragma unroll
                    for (int nt = 0; nt < 4; ++nt)
                        acc[mt][nt] = __builtin_amdgcn_mfma_f32_16x16x32_bf16(
                            af[mt], bfr[nt], acc[mt][nt], 0, 0, 0);
            }
            __syncthreads();
        }
    }

    // Epilogue: bias + relu, conv1 -> LDS bf16 [128 px][128 o], same XOR swizzle
    float bias[4];
    #pragma unroll
    for (int nt = 0; nt < 4; ++nt) bias[nt] = b_conv[chunk * 128 + ncol + nt * 16 + mr];
    #pragma unroll
    for (int mt = 0; mt < 4; ++mt)
        #pragma unroll
        for (int nt = 0; nt < 4; ++nt)
            #pragma unroll
            for (int q = 0; q < 4; ++q) {
                int row = mrow + mt * 16 + (lane >> 4) * 4 + q;
                int col = ncol + nt * 16 + mr;
                int sl  = (col >> 3) ^ (row & 7);
                smem[row * 128 + (sl << 3) + (col & 7)] =
                    f2bf(fmaxf(acc[mt][nt][q] + bias[nt], 0.0f));
            }
    __syncthreads();

    // Head GEMM: [128 px x 128 o] @ Wh2^T chunk -> [128 px x 32 j]
    f32x4 acc2[2][2];
    #pragma unroll
    for (int mi = 0; mi < 2; ++mi)
        #pragma unroll
        for (int ni = 0; ni < 2; ++ni) acc2[mi][ni] = (f32x4){0.f, 0.f, 0.f, 0.f};
    #pragma unroll
    for (int ks = 0; ks < 4; ++ks) {
        const int sg = ks * 4 + (lane >> 4);          // logical 16B slot 0..15
        bf16x8 ha[2], hb[2];
        #pragma unroll
        for (int mi = 0; mi < 2; ++mi) {
            int rowH = (wv * 2 + mi) * 16 + mr;
            ha[mi] = *(const bf16x8*)&smem[rowH * 128 + ((sg ^ m7) << 3)];
        }
        #pragma unroll
        for (int ni = 0; ni < 2; ++ni)
            hb[ni] = *(const bf16x8*)&wh2[(ni * 16 + mr) * 512 + chunk * 128 + ks * 32 + kq];
        #pragma unroll
        for (int mi = 0; mi < 2; ++mi)
            #pragma unroll
            for (int ni = 0; ni < 2; ++ni)
                acc2[mi][ni] = __builtin_amdgcn_mfma_f32_16x16x32_bf16(
                    ha[mi], hb[ni], acc2[mi][ni], 0, 0, 0);
    }
    const long slotbase = (long)tile * 128;
    #pragma unroll
    for (int ni = 0; ni < 2; ++ni) {
        int j = ni * 16 + mr;
        if (j < 18) {
            #pragma unroll
            for (int mi = 0; mi < 2; ++mi)
                #pragma unroll
                for (int q = 0; q < 4; ++q) {
                    int row = (wv * 2 + mi) * 16 + (lane >> 4) * 4 + q;
                    atomicAdd(&sbuf[(slotbase + row) * 18 + j], acc2[mi][ni][q]);
                }
        }
    }
}

// ---------------------------------------------------------------------------
// Kernel 4: finalize. slot -> (b,level,hp,wp); biases, paired sigmoid-softmax
// (partner = c +/- 3), scatter into the 3 concatenated outputs.
// ---------------------------------------------------------------------------
__global__ __launch_bounds__(256) void finalize(
    const float* __restrict__ sbuf, const float* __restrict__ b_cls,
    const float* __restrict__ b_box, float* __restrict__ out)
{
    int idx = blockIdx.x * 256 + threadIdx.x;      // < 204288
    int tile = idx >> 7, m = idx & 127;
    int b = tile / 399;
    int tr = tile - b * 399;
    int hp, wp, H, W, noff;
    if (tr < 296)      { int f = 252 + (tr)       * 128 + m; hp = f / 252; wp = f - hp * 252; H = 150; W = 250; noff = 0; }
    else if (tr < 371) { int f = 127 + (tr - 296) * 128 + m; hp = f / 127; wp = f - hp * 127; H = 75;  W = 125; noff = 112500; }
    else if (tr < 391) { int f = 65  + (tr - 371) * 128 + m; hp = f / 65;  wp = f - hp * 65;  H = 38;  W = 63;  noff = 140625; }
    else if (tr < 397) { int f = 34  + (tr - 391) * 128 + m; hp = f / 34;  wp = f - hp * 34;  H = 19;  W = 32;  noff = 147807; }
    else               { int f = 18  + (tr - 397) * 128 + m; hp = f / 18;  wp = f - hp * 18;  H = 10;  W = 16;  noff = 149631; }
    if (hp < 1 || hp > H || wp < 1 || wp > W) return;

    const float* s = sbuf + (long)idx * 18;
    float sc[6], bb[12], pr[6];
    #pragma unroll
    for (int c = 0; c < 6; ++c) sc[c] = s[c] + b_cls[c];
    #pragma unroll
    for (int k = 0; k < 12; ++k) bb[k] = s[6 + k] + b_box[k];
    #pragma unroll
    for (int c = 0; c < 6; ++c) {
        int p = (c < 3) ? c + 3 : c - 3;
        pr[c] = 1.0f / (1.0f + expf(sc[p] - sc[c]));
    }
    int n = noff + ((hp - 1) * W + (wp - 1)) * 3;
    long o0 = ((long)b * 150111 + n) * 2;
    float* O0 = out + o0;
    float* O1 = out + 1200888 + o0;
    float* O2 = out + 2401776 + ((long)b * 150111 + n) * 4;
    #pragma unroll
    for (int c = 0; c < 6; ++c) { O0[c] = sc[c]; O1[c] = pr[c]; }
    #pragma unroll
    for (int k = 0; k < 12; ++k) O2[k] = bb[k];
}

// ---------------------------------------------------------------------------
extern "C" void kernel_launch(void* const* d_in, const int* in_sizes, int n_in,
                              void* d_out, int out_size, void* d_ws, size_t ws_size,
                              hipStream_t stream)
{
    const float* f0   = (const float*)d_in[0];
    const float* f1   = (const float*)d_in[1];
    const float* f2   = (const float*)d_in[2];
    const float* f3   = (const float*)d_in[3];
    const float* f4   = (const float*)d_in[4];
    // d_in[5] = im_info (unused by reference math)
    const float* Wc   = (const float*)d_in[6];
    const float* bC   = (const float*)d_in[7];
    const float* Wcls = (const float*)d_in[8];
    const float* bcls = (const float*)d_in[9];
    const float* Wbox = (const float*)d_in[10];
    const float* bbox = (const float*)d_in[11];

    unsigned short* wr2  = (unsigned short*)((char*)d_ws + WS_WR2_OFF);
    unsigned short* wh2  = (unsigned short*)((char*)d_ws + WS_WH2_OFF);
    float*          sbuf = (float*)((char*)d_ws + WS_SB_OFF);
    unsigned short* fpad = (unsigned short*)((char*)d_ws + WS_FP_OFF);

    // Zero only what correctness needs: sbuf (atomic init) + pad rings + wh2 tail.
    hipMemsetAsync((char*)d_ws + WS_SB_OFF, 0, (size_t)(WS_FP_OFF - WS_SB_OFF), stream);
    hipLaunchKernelGGL(prep_weights, dim3(4672), dim3(256), 0, stream, Wc, Wcls, Wbox, wr2, wh2);
    hipLaunchKernelGGL(zero_rings,   dim3(788),  dim3(256), 0, stream, fpad);
    hipLaunchKernelGGL(prep_feats,   dim3(3268), dim3(256), 0, stream, f0, f1, f2, f3, f4, fpad);
    hipLaunchKernelGGL(conv_main,    dim3(6400), dim3(256), 0, stream, fpad, wr2, wh2, bC, sbuf);
    hipLaunchKernelGGL(finalize,     dim3(798),  dim3(256), 0, stream, sbuf, bcls, bbox, (float*)d_out);
}